// Round 8
// baseline (5857.436 us; speedup 1.0000x reference)
//
#include <hip/hip_runtime.h>

// ---------------------------------------------------------------------------
// 2-layer LSTM, T=1024, B=32, D=256, H=512. Inputs fp32, OUTPUT fp32.
//   pack_w3: fp32 {W_hh0, W_hh1, W_ih1} -> bf16 MFMA B-fragment order.
//   gemm_xp: xp0 = x @ W_ih0^T (bf16 MFMA).
//   lstm_fused: persistent 32-wg x 512-thread kernel. wgs 0..15 = layer0,
//     16..31 = layer1 (lag 1 step, consumes hs0[t] + register-resident Wih1).
//     Fence-free relaxed agent-atomic exchange (R5/R6); batched atomic loads
//     -> LDS mirrors; 16-wide barrier fan-in (was 32); both poll phases merged
//     at top of step (lanes 0-15: other-layer, 16-31: own-layer t-1).
// ---------------------------------------------------------------------------

typedef __bf16 bf16x8 __attribute__((ext_vector_type(8)));
typedef float  f32x4  __attribute__((ext_vector_type(4)));
typedef float  f32x2  __attribute__((ext_vector_type(2)));
typedef unsigned long long u64;
typedef unsigned int u32;

#define MFMA16(a, b, c) __builtin_amdgcn_mfma_f32_16x16x32_bf16((a), (b), (c), 0, 0, 0)
#define SCOPE_AGENT __HIP_MEMORY_SCOPE_AGENT

__device__ __forceinline__ float fsigm(float x) { return 1.0f / (1.0f + __expf(-x)); }
__device__ __forceinline__ float ftanh(float x) {
    x = fminf(15.0f, fmaxf(-15.0f, x));
    float e = __expf(2.0f * x);
    return (e - 1.0f) / (e + 1.0f);
}

__device__ __forceinline__ bf16x8 frag_from(u64 lo, u64 hi) {
    union { u64 u[2]; bf16x8 v; } x;
    x.u[0] = lo; x.u[1] = hi;
    return x.v;
}

// ---------------------------------------------------------------------------
// Pack [2048][512] fp32 -> 128 wave-slices of bf16 B-fragment order (slice
// s = w'*4+v' covers gate v', h-cols w'*16..+16):
//   WB[(s*16+kk)*512 + lane*8 + e] = bf16(W[v'*512 + w'*16 + (lane&15)][k0+e])
// ---------------------------------------------------------------------------
__global__ void pack_w3(const float* __restrict__ W0, const float* __restrict__ W1,
                        const float* __restrict__ W2, __bf16* __restrict__ O0,
                        __bf16* __restrict__ O1, __bf16* __restrict__ O2) {
    int gtid = blockIdx.x * 256 + threadIdx.x;          // 0 .. 393215
    int sel  = gtid >> 17;                              // 0,1,2
    const float* W = (sel == 0) ? W0 : (sel == 1) ? W1 : W2;
    __bf16* WB     = (sel == 0) ? O0 : (sel == 1) ? O1 : O2;
    int tid  = gtid & 131071;
    int lane = tid & 63;
    int kk   = (tid >> 6) & 15;
    int v    = (tid >> 10) & 3;
    int w    = tid >> 12;                               // 0..31
    int n    = v * 16 + (lane & 15);
    int grow = (n >> 4) * 512 + w * 16 + (n & 15);
    int k0   = kk * 32 + (lane >> 4) * 8;
    const float* src = W + (size_t)grow * 512 + k0;
    bf16x8 val;
#pragma unroll
    for (int e = 0; e < 8; e++) val[e] = (__bf16)src[e];
    *(bf16x8*)(WB + (size_t)tid * 8) = val;
}

// ---------------------------------------------------------------------------
// xp0[r][n] = sum_k x_perm(r)[k] * W[n][k], r = t*32+b, x is [B,T,D] fp32.
// ---------------------------------------------------------------------------
__global__ __launch_bounds__(256, 2) void gemm_xp(const float* __restrict__ A,
                                                  const float* __restrict__ W,
                                                  __bf16* __restrict__ out, int K) {
    const int tid = threadIdx.x, lane = tid & 63, wv = tid >> 6;
    const int bm = blockIdx.x >> 4, bn = blockIdx.x & 15;
    const int m_base = bm * 128 + (wv & 1) * 64;
    const int n_base = bn * 128 + (wv >> 1) * 64;
    const int kq = (lane >> 4) * 8;
    const int rl = lane & 15;

    f32x4 acc[4][4];
#pragma unroll
    for (int i = 0; i < 4; i++)
#pragma unroll
        for (int j = 0; j < 4; j++) acc[i][j] = (f32x4){0.f, 0.f, 0.f, 0.f};

    const int nk = K >> 5;
    for (int kk = 0; kk < nk; kk++) {
        int k0 = kk * 32 + kq;
        bf16x8 af[4], bfr[4];
#pragma unroll
        for (int mt = 0; mt < 4; mt++) {
            int row = m_base + mt * 16 + rl;
            const float* ap = A + (size_t)((row & 31) * 1024 + (row >> 5)) * K + k0;
#pragma unroll
            for (int e = 0; e < 8; e++) af[mt][e] = (__bf16)ap[e];
        }
#pragma unroll
        for (int nt = 0; nt < 4; nt++) {
            int n = n_base + nt * 16 + rl;
            const float* wp = W + (size_t)n * K + k0;
#pragma unroll
            for (int e = 0; e < 8; e++) bfr[nt][e] = (__bf16)wp[e];
        }
#pragma unroll
        for (int mt = 0; mt < 4; mt++)
#pragma unroll
            for (int nt = 0; nt < 4; nt++)
                acc[mt][nt] = MFMA16(af[mt], bfr[nt], acc[mt][nt]);
    }

    const int rq = (lane >> 4) * 4;
#pragma unroll
    for (int mt = 0; mt < 4; mt++)
#pragma unroll
        for (int nt = 0; nt < 4; nt++)
#pragma unroll
            for (int r = 0; r < 4; r++) {
                int row = m_base + mt * 16 + rq + r;
                int col = n_base + nt * 16 + rl;
                out[(size_t)row * 2048 + col] = (__bf16)acc[mt][nt][r];
            }
}

// ---------------------------------------------------------------------------
// Fused pipelined recurrence: 32 wgs x 512 threads. wg<16: layer0 (w=wg);
// wg>=16: layer1 (w=wg-16), lagging 1 step. wg owns h-cols w*32..+32 for all
// 4 gates (128 gate-cols); wave v (0..7) = old slice (w*2+(v>>2), v&3).
// Top-of-step merged poll; flag[t] set at end of step t (after that wg's
// staging reads -> WAR on double buffer stays guarded).
// ---------------------------------------------------------------------------
__global__ __launch_bounds__(512, 1) void lstm_fused(
    const __bf16* __restrict__ xp0,   // [32768][2048] bf16, row = t*32+b
    const __bf16* __restrict__ WB0,   // W_hh0 packed
    const __bf16* __restrict__ WB1,   // W_hh1 packed
    const __bf16* __restrict__ WBi1,  // W_ih1 packed
    const float* __restrict__ bias0,
    const float* __restrict__ bias1,
    __bf16* __restrict__ hbuf0,       // [2][32][512] zeroed
    __bf16* __restrict__ hbuf1,       // [2][32][512] zeroed
    __bf16* __restrict__ hs0_bf,      // [1024*32][512]
    float* __restrict__ out_f32,      // [32][1024][512]
    float* __restrict__ hn_out,       // [2][32][512]
    float* __restrict__ cn_out,       // [2][32][512]
    int* __restrict__ flags0,         // [16][1024] zeroed (private line per wg)
    int* __restrict__ flags1) {       // [16][1024] zeroed
    const int tid   = threadIdx.x;
    const int wg    = blockIdx.x;   // 0..31
    const int layer = wg >> 4;
    const int w     = wg & 15;
    const int lane  = tid & 63;
    const int v     = tid >> 6;     // wave 0..7

    __shared__ __bf16 h_lds[32 * 516];  // own-state mirror (stride 516)
    __shared__ __bf16 s_lds[32 * 516];  // hs0[t] mirror (layer1)
    __shared__ float  g_lds[32 * 132];  // gates [32 b][128 cols +4]

    // --- weights resident in registers; wave slice = (w*2+(v>>2), v&3) ---
    bf16x8 wregA[16], wregB[16];
    {
        const int s = (w * 2 + (v >> 2)) * 4 + (v & 3);
        const size_t wo = (size_t)s * 16 * 512 + lane * 8;
        const __bf16* wa = (layer ? WB1 : WB0) + wo;
#pragma unroll
        for (int kk = 0; kk < 16; kk++) wregA[kk] = *(const bf16x8*)(wa + kk * 512);
        if (layer) {
            const __bf16* wb = WBi1 + wo;
#pragma unroll
            for (int kk = 0; kk < 16; kk++) wregB[kk] = *(const bf16x8*)(wb + kk * 512);
        }
    }

    const float* bias = layer ? bias1 : bias0;
    __bf16* hbuf  = layer ? hbuf1 : hbuf0;
    int* flagsMy  = layer ? flags1 : flags0;

    // --- elementwise mapping: thread -> (b, j0, j0+1) ---
    const int b  = tid >> 4;            // 0..31
    const int jp = tid & 15;            // 0..15
    const int j0 = w * 32 + jp * 2;     // global h column (even)
    const int jw = jp * 2;              // within-wg col
    const int gcbase = (jw >> 4) * 64 + (jw & 15);  // g_lds col for gate 0
    f32x2 bsv[4];
#pragma unroll
    for (int g = 0; g < 4; g++) bsv[g] = *(const f32x2*)(bias + g * 512 + j0);
    float cc0 = 0.f, cc1 = 0.f;

    const int arow = lane & 15;
    const int kq8  = (lane >> 4) * 8;

    // xp prefetch (layer0 only)
    u32 xc[4] = {0, 0, 0, 0}, xn[4] = {0, 0, 0, 0};
    if (!layer) {
#pragma unroll
        for (int g = 0; g < 4; g++)
            xc[g] = *(const u32*)(xp0 + (size_t)b * 2048 + g * 512 + j0);
    }

    for (int t = 0; t < 1024; t++) {
        // --- merged top-of-step poll ---
        if (!layer) {
            int tn = (t < 1023) ? t + 1 : 1023;
#pragma unroll
            for (int g = 0; g < 4; g++)
                xn[g] = *(const u32*)(xp0 + (size_t)(tn * 32 + b) * 2048 + g * 512 + j0);
            if (t > 0) {
                if (tid < 16) {
                    while (__hip_atomic_load(&flags0[tid * 1024 + t - 1], __ATOMIC_RELAXED,
                                             SCOPE_AGENT) == 0) {}
                }
                asm volatile("" ::: "memory");
                __syncthreads();
            }
        } else {
            if (tid < 16) {
                while (__hip_atomic_load(&flags0[tid * 1024 + t], __ATOMIC_RELAXED,
                                         SCOPE_AGENT) == 0) {}
            } else if (tid < 32 && t > 0) {
                while (__hip_atomic_load(&flags1[(tid - 16) * 1024 + t - 1], __ATOMIC_RELAXED,
                                         SCOPE_AGENT) == 0) {}
            }
            asm volatile("" ::: "memory");
            __syncthreads();
        }

        // --- stage own h state (and hs0[t] for layer1): batched atomic loads ---
        {
            const u64* hg = (const u64*)(hbuf + (size_t)(t & 1) * 16384);
            u64 hv[8];
#pragma unroll
            for (int i = 0; i < 8; i++)
                hv[i] = __hip_atomic_load(hg + i * 512 + tid, __ATOMIC_RELAXED, SCOPE_AGENT);
            if (layer) {
                const u64* sg = (const u64*)(hs0_bf + (size_t)t * 16384);
                u64 sv[8];
#pragma unroll
                for (int i = 0; i < 8; i++)
                    sv[i] = __hip_atomic_load(sg + i * 512 + tid, __ATOMIC_RELAXED, SCOPE_AGENT);
#pragma unroll
                for (int i = 0; i < 8; i++) {
                    int f  = (i * 512 + tid) * 4;
                    int br = f >> 9, col = f & 511;
                    *(u64*)(s_lds + br * 516 + col) = sv[i];
                }
            }
#pragma unroll
            for (int i = 0; i < 8; i++) {
                int f  = (i * 512 + tid) * 4;
                int br = f >> 9, col = f & 511;
                *(u64*)(h_lds + br * 516 + col) = hv[i];
            }
        }
        __syncthreads();

        // --- MFMA: gates[b][gatecol] = h @ Whh^T (+ hs0 @ Wih1^T) ---
        f32x4 acc0 = (f32x4){0.f, 0.f, 0.f, 0.f};
        f32x4 acc1 = (f32x4){0.f, 0.f, 0.f, 0.f};
#pragma unroll
        for (int kk = 0; kk < 16; kk++) {
            const __bf16* p0 = h_lds + arow * 516 + kq8 + kk * 32;
            const __bf16* p1 = p0 + 16 * 516;
            bf16x8 a0 = frag_from(*(const u64*)p0, *(const u64*)(p0 + 4));
            bf16x8 a1 = frag_from(*(const u64*)p1, *(const u64*)(p1 + 4));
            acc0 = MFMA16(a0, wregA[kk], acc0);
            acc1 = MFMA16(a1, wregA[kk], acc1);
        }
        if (layer) {
#pragma unroll
            for (int kk = 0; kk < 16; kk++) {
                const __bf16* p0 = s_lds + arow * 516 + kq8 + kk * 32;
                const __bf16* p1 = p0 + 16 * 516;
                bf16x8 a0 = frag_from(*(const u64*)p0, *(const u64*)(p0 + 4));
                bf16x8 a1 = frag_from(*(const u64*)p1, *(const u64*)(p1 + 4));
                acc0 = MFMA16(a0, wregB[kk], acc0);
                acc1 = MFMA16(a1, wregB[kk], acc1);
            }
        }
        {
            int col   = v * 16 + (lane & 15);
            int rbase = (lane >> 4) * 4;
#pragma unroll
            for (int r = 0; r < 4; r++) {
                g_lds[(rbase + r) * 132 + col]      = acc0[r];
                g_lds[(16 + rbase + r) * 132 + col] = acc1[r];
            }
        }
        __syncthreads();

        // --- gate math: thread owns (b, j0, j0+1) ---
        float hf0, hf1;
        {
            union { u32 u; __bf16 v2[2]; } xi, xf, xg, xo;
            xi.u = xc[0]; xf.u = xc[1]; xg.u = xc[2]; xo.u = xc[3];
            const float* gl = g_lds + b * 132 + gcbase;
            f32x2 gi = *(const f32x2*)(gl);
            f32x2 gf = *(const f32x2*)(gl + 16);
            f32x2 gg = *(const f32x2*)(gl + 32);
            f32x2 go = *(const f32x2*)(gl + 48);

            float i0 = fsigm(gi[0] + (float)xi.v2[0] + bsv[0][0]);
            float f0 = fsigm(gf[0] + (float)xf.v2[0] + bsv[1][0]);
            float g0 = ftanh(gg[0] + (float)xg.v2[0] + bsv[2][0]);
            float o0 = fsigm(go[0] + (float)xo.v2[0] + bsv[3][0]);
            cc0 = f0 * cc0 + i0 * g0;
            hf0 = o0 * ftanh(cc0);

            float i1 = fsigm(gi[1] + (float)xi.v2[1] + bsv[0][1]);
            float f1 = fsigm(gf[1] + (float)xf.v2[1] + bsv[1][1]);
            float g1 = ftanh(gg[1] + (float)xg.v2[1] + bsv[2][1]);
            float o1 = fsigm(go[1] + (float)xo.v2[1] + bsv[3][1]);
            cc1 = f1 * cc1 + i1 * g1;
            hf1 = o1 * ftanh(cc1);
        }
        union { __bf16 v2[2]; u32 u; } hu;
        hu.v2[0] = (__bf16)hf0; hu.v2[1] = (__bf16)hf1;

        // h store + (layer0) hs0[t] store — both pre-flag, atomic
        __bf16* hnx = hbuf + (size_t)((t + 1) & 1) * 16384;
        __hip_atomic_store((u32*)(hnx + (size_t)b * 512 + j0), hu.u,
                           __ATOMIC_RELAXED, SCOPE_AGENT);
        if (!layer)
            __hip_atomic_store((u32*)(hs0_bf + ((size_t)t * 32 + b) * 512 + j0), hu.u,
                               __ATOMIC_RELAXED, SCOPE_AGENT);

        // --- drain + flag (private line per wg); overlap tail stores ---
        asm volatile("s_waitcnt vmcnt(0)" ::: "memory");
        __syncthreads();
        if (tid == 0 && (t < 1023 || !layer))
            __hip_atomic_store(&flagsMy[w * 1024 + t], 1, __ATOMIC_RELAXED, SCOPE_AGENT);

        if (layer) {
            f32x2 hf2 = (f32x2){hf0, hf1};
            *(f32x2*)(out_f32 + (size_t)b * 524288 + (size_t)t * 512 + j0) = hf2;
        }
        if (t == 1023) {
            float* hn = hn_out + (size_t)layer * 16384;
            float* cn = cn_out + (size_t)layer * 16384;
            *(f32x2*)(hn + (size_t)b * 512 + j0) = (f32x2){hf0, hf1};
            *(f32x2*)(cn + (size_t)b * 512 + j0) = (f32x2){cc0, cc1};
        }
#pragma unroll
        for (int g = 0; g < 4; g++) xc[g] = xn[g];
    }
}

// ---------------------------------------------------------------------------
extern "C" void kernel_launch(void* const* d_in, const int* in_sizes, int n_in,
                              void* d_out, int out_size, void* d_ws, size_t ws_size,
                              hipStream_t stream) {
    (void)in_sizes; (void)n_in; (void)out_size; (void)ws_size;
    const float* x    = (const float*)d_in[0];  // [32][1024][256] fp32
    const float* Wih0 = (const float*)d_in[1];  // [2048][256] fp32
    const float* b0   = (const float*)d_in[2];  // [2048] fp32
    const float* Whh0 = (const float*)d_in[3];  // [2048][512] fp32
    const float* Wih1 = (const float*)d_in[4];  // [2048][512] fp32
    const float* b1   = (const float*)d_in[5];  // [2048] fp32
    const float* Whh1 = (const float*)d_in[6];  // [2048][512] fp32
    float* dout = (float*)d_out;  // fp32: out(16777216) | h_n(2*16384) | c_n(2*16384)

    char* wsb = (char*)d_ws;
    int*    flags0 = (int*)wsb;                                  // 64 KB used
    int*    flags1 = (int*)(wsb + (128 << 10));                  // 64 KB used
    __bf16* hbuf0  = (__bf16*)(wsb + (256 << 10));               // 64 KB
    __bf16* hbuf1  = (__bf16*)(wsb + (320 << 10));               // 64 KB
    __bf16* WB0    = (__bf16*)(wsb + (384 << 10));               // 2 MB
    __bf16* WB1    = (__bf16*)(wsb + (384 << 10) + (2 << 20));   // 2 MB
    __bf16* WBi1   = (__bf16*)(wsb + (384 << 10) + (4 << 20));   // 2 MB
    __bf16* hs0    = (__bf16*)(wsb + (384 << 10) + (6 << 20));   // 32 MB
    __bf16* xpb    = (__bf16*)(wsb + (384 << 10) + (38 << 20));  // 128 MB

    // zero flags + both h double-buffers (contiguous 384 KB)
    (void)hipMemsetAsync(wsb, 0, 384 << 10, stream);

    pack_w3<<<dim3(1536), dim3(256), 0, stream>>>(Whh0, Whh1, Wih1, WB0, WB1, WBi1);

    // xp0 = x @ Wih0^T  (K=256, fp32 A, permuted rows)
    gemm_xp<<<dim3(4096), dim3(256), 0, stream>>>(x, Wih0, xpb, 256);

    lstm_fused<<<dim3(32), dim3(512), 0, stream>>>(
        xpb, WB0, WB1, WBi1, b0, b1, hbuf0, hbuf1, hs0,
        dout, dout + 16777216, dout + 16777216 + 32768, flags0, flags1);
}